// Round 2
// baseline (734.375 us; speedup 1.0000x reference)
//
#include <hip/hip_runtime.h>

// Sobel3D fused (fp32): computes gx, gy, gz (depthwise separable 3x3x3) in one
// pass. R0 post-mortem: input/output are FLOAT32 per the reference dtypes
// (bf16-bit reinterpretation produced NaN from garbage exponents).
//
// Decomposition (XLA conv = cross-correlation, no kernel flip):
//   per plane z: A = S_h*D_w, B = D_h*S_w, C = S_h*S_w   (2D combos)
//   gx[d] = A(d-1) + 2A(d) + A(d+1)
//   gy[d] = B(d-1) + 2B(d) + B(d+1)
//   gz[d] = C(d+1) - C(d-1)
// Thread: 4 consecutive w (float4, 16B I/O), rolls along d. w-halo via wave
// shuffles (edge lanes are the zero-pad boundary), h-halo via direct loads
// (cache-served), d-halo via rolling registers.

#define DDIM 96
#define HDIM 128
#define WDIM 128
#define NCIMG 32                                  // N*C = 2*16
#define NTOT ((size_t)NCIMG * DDIM * HDIM * WDIM) // 50331648 per output tensor
#define DCHUNK 24

__global__ __launch_bounds__(256, 2)
void sobel3d_fused(const float* __restrict__ x, float* __restrict__ out) {
  const int wx = threadIdx.x;            // 0..31 (w-chunk within row)
  const int w0 = wx << 2;                // 0,4,...,124
  const int h  = blockIdx.y * 8 + threadIdx.y;
  const int nc = blockIdx.z >> 2;        // image index 0..31
  const int d0 = (blockIdx.z & 3) * DCHUNK;

  const float* img = x + (size_t)nc * DDIM * HDIM * WDIM;

  float A0[4], B0[4], C0[4], A1[4], B1[4], C1[4], A2[4], B2[4], C2[4];

  // Compute the three 2D combos for plane z at this thread's (h, w0..w0+3).
  auto combos = [&](int z, float* A, float* B, float* C) {
#pragma unroll
    for (int j = 0; j < 4; ++j) { A[j] = 0.f; B[j] = 0.f; C[j] = 0.f; }
#pragma unroll
    for (int r = 0; r < 3; ++r) {        // rows h-1, h, h+1
      const int hh = h - 1 + r;
      const float s = (hh >= 0 && hh < HDIM) ? 1.f : 0.f;  // zero-pad rows
      const int hc = hh < 0 ? 0 : (hh >= HDIM ? HDIM - 1 : hh);
      const float4 v = *(const float4*)(img + ((size_t)z * HDIM + hc) * WDIM + w0);
      float xr[4] = {v.x, v.y, v.z, v.w};
      // w-halo from neighboring lanes (uniform control flow -> shuffles safe).
      // Lanes within a row are contiguous (blockDim.x=32); wx==0 / wx==31 are
      // exactly the w-pad boundaries and get zeroed, so cross-row shuffle
      // leakage at the wave midpoint never contributes.
      float xm = __shfl_up(xr[3], 1);    // left neighbor's element 3  (w0-1)
      float xp = __shfl_down(xr[0], 1);  // right neighbor's element 0 (w0+4)
      if (wx == 0)  xm = 0.f;            // w = -1  -> zero pad
      if (wx == 31) xp = 0.f;            // w = 128 -> zero pad
      xm *= s; xp *= s;
#pragma unroll
      for (int j = 0; j < 4; ++j) xr[j] *= s;
      float P[4], Q[4];                  // P = S_w, Q = D_w along this row
      P[0] = xm + 2.f * xr[0] + xr[1];   Q[0] = xr[1] - xm;
      P[1] = xr[0] + 2.f * xr[1] + xr[2]; Q[1] = xr[2] - xr[0];
      P[2] = xr[1] + 2.f * xr[2] + xr[3]; Q[2] = xr[3] - xr[1];
      P[3] = xr[2] + 2.f * xr[3] + xp;   Q[3] = xp - xr[2];
#pragma unroll
      for (int j = 0; j < 4; ++j) {
        if (r == 0) { A[j] += Q[j];       B[j] -= P[j]; C[j] += P[j]; }
        if (r == 1) { A[j] += 2.f * Q[j];               C[j] += 2.f * P[j]; }
        if (r == 2) { A[j] += Q[j];       B[j] += P[j]; C[j] += P[j]; }
      }
    }
  };

  // Prime rolling planes: d0-1 (zero if OOB) and d0.
  {
    const int zm = d0 - 1;
    combos(zm < 0 ? 0 : zm, A0, B0, C0);
    if (zm < 0) {
#pragma unroll
      for (int j = 0; j < 4; ++j) { A0[j] = 0.f; B0[j] = 0.f; C0[j] = 0.f; }
    }
  }
  combos(d0, A1, B1, C1);

  for (int d = d0; d < d0 + DCHUNK; ++d) {
    const int zp = d + 1;
    combos(zp >= DDIM ? DDIM - 1 : zp, A2, B2, C2);   // uniform clamp
    if (zp >= DDIM) {
#pragma unroll
      for (int j = 0; j < 4; ++j) { A2[j] = 0.f; B2[j] = 0.f; C2[j] = 0.f; }
    }

    const size_t o = (((size_t)nc * DDIM + d) * HDIM + h) * WDIM + w0;
    float4 gx, gy, gz;
    gx.x = A0[0] + 2.f * A1[0] + A2[0];
    gx.y = A0[1] + 2.f * A1[1] + A2[1];
    gx.z = A0[2] + 2.f * A1[2] + A2[2];
    gx.w = A0[3] + 2.f * A1[3] + A2[3];
    gy.x = B0[0] + 2.f * B1[0] + B2[0];
    gy.y = B0[1] + 2.f * B1[1] + B2[1];
    gy.z = B0[2] + 2.f * B1[2] + B2[2];
    gy.w = B0[3] + 2.f * B1[3] + B2[3];
    gz.x = C2[0] - C0[0];
    gz.y = C2[1] - C0[1];
    gz.z = C2[2] - C0[2];
    gz.w = C2[3] - C0[3];
    *(float4*)(out + o)            = gx;
    *(float4*)(out + NTOT + o)     = gy;
    *(float4*)(out + 2 * NTOT + o) = gz;

#pragma unroll
    for (int j = 0; j < 4; ++j) {        // roll planes
      A0[j] = A1[j]; B0[j] = B1[j]; C0[j] = C1[j];
      A1[j] = A2[j]; B1[j] = B2[j]; C1[j] = C2[j];
    }
  }
}

extern "C" void kernel_launch(void* const* d_in, const int* in_sizes, int n_in,
                              void* d_out, int out_size, void* d_ws, size_t ws_size,
                              hipStream_t stream) {
  const float* x = (const float*)d_in[0];
  float* out = (float*)d_out;
  dim3 block(32, 8, 1);
  dim3 grid(1, HDIM / 8, NCIMG * (DDIM / DCHUNK));  // (1, 16, 128)
  hipLaunchKernelGGL(sobel3d_fused, grid, block, 0, stream, x, out);
}